// Round 3
// baseline (722.759 us; speedup 1.0000x reference)
//
#include <hip/hip_runtime.h>
#include <hip/hip_bf16.h>
#include <stdint.h>

#define D_IN 118
#define D_OUT 64
#define KPAD 128
#define MAXSEG 16   // per-block LDS segment window (4 KB); overflow -> direct atomics

typedef __attribute__((ext_vector_type(8))) short bf16x8;
typedef __attribute__((ext_vector_type(4))) float floatx4;

// round-to-nearest-even fp32 -> bf16
__device__ __forceinline__ uint16_t f2bf(float f) {
    uint32_t u;
    __builtin_memcpy(&u, &f, 4);
    return (uint16_t)((u + 0x7fffu + ((u >> 16) & 1u)) >> 16);
}

__device__ __forceinline__ uint32_t pack_bf16(float a, float b) {
    return (uint32_t)f2bf(a) | ((uint32_t)f2bf(b) << 16);
}

__global__ void wconv(const float* __restrict__ W, ushort* __restrict__ Wt) {
    int idx = blockIdx.x * 256 + threadIdx.x;  // 8192 total
    if (idx >= D_OUT * KPAD) return;
    int o = idx >> 7, k = idx & 127;
    float v = (k < D_IN) ? W[o * D_IN + k] : 0.f;
    Wt[idx] = f2bf(v);
}

// LDS-free GEMM: each wave owns 16 atom rows x all 64 outputs.
// A-fragments read straight from global in MFMA lane layout (float2-aligned),
// packed to bf16 in-register. No staging barrier; occupancy is VGPR-bound.
__global__ __launch_bounds__(256) void fused_main(
    const float* __restrict__ x, const ushort* __restrict__ Wt,
    const float* __restrict__ bias, const int* __restrict__ batch,
    float* __restrict__ out, int n_atoms)
{
    __shared__ float segacc[MAXSEG * 64];  // 4 KB block-level segment accumulator

    const int tid = threadIdx.x;
    const int lane = tid & 63;
    const int wv = tid >> 6;
    const int n = lane & 15;   // MFMA A-row / B-col / D-col
    const int q = lane >> 4;   // quad

    // zero segacc, then one cheap barrier before any flushes
#pragma unroll
    for (int i = 0; i < (MAXSEG * 64) / 256; ++i)
        segacc[i * 256 + tid] = 0.0f;
    __syncthreads();

    const int rowbase = blockIdx.x * 64 + wv * 16;
    const int myrow = rowbase + n;
    const bool rok = myrow < n_atoms;
    const float* __restrict__ arow = x + (long)myrow * D_IN;

    floatx4 acc[4];
#pragma unroll
    for (int ot = 0; ot < 4; ++ot) acc[ot] = (floatx4){0.f, 0.f, 0.f, 0.f};

#pragma unroll 1
    for (int ks = 0; ks < 4; ++ks) {
        const int k0 = ks * 32 + q * 8;
        uint32_t pk[4];
#pragma unroll
        for (int j2 = 0; j2 < 4; ++j2) {
            int k = k0 + j2 * 2;
            float2 v = make_float2(0.f, 0.f);
            if (rok && k + 1 < D_IN)  // uniform-true except ks==3 tail
                v = *reinterpret_cast<const float2*>(arow + k);
            pk[j2] = pack_bf16(v.x, v.y);
        }
        bf16x8 afrag;
        __builtin_memcpy(&afrag, pk, 16);

#pragma unroll
        for (int ot = 0; ot < 4; ++ot) {
            bf16x8 bfrag = *reinterpret_cast<const bf16x8*>(
                Wt + (ot * 16 + n) * KPAD + k0);  // L1-hot, 16 KB total
            acc[ot] = __builtin_amdgcn_mfma_f32_16x16x32_bf16(
                afrag, bfrag, acc[ot], 0, 0, 0);
        }
    }

    // ---- epilogue: bias + relu + sorted-run flush -> LDS segacc -> global ----
    float bv[4];
#pragma unroll
    for (int ot = 0; ot < 4; ++ot) bv[ot] = bias[ot * 16 + n];

    // lane holds D rows rowbase + q*4 + reg, cols ot*16 + n
    int idr = rowbase + q * 4;
    int4 myids = make_int4(-1, -1, -1, -1);
    if (idr + 3 < n_atoms) {
        myids = *reinterpret_cast<const int4*>(batch + idr);  // 16B-aligned
    } else if (idr < n_atoms) {
        const int* bp = batch + idr;
        myids.x = bp[0];
        if (idr + 1 < n_atoms) myids.y = bp[1];
        if (idr + 2 < n_atoms) myids.z = bp[2];
    }
    int ids4[4] = {myids.x, myids.y, myids.z, myids.w};

    const int s_first = batch[blockIdx.x * 64];  // wave-uniform broadcast

    float racc[4] = {0.f, 0.f, 0.f, 0.f};
    int cur = ids4[0];
#pragma unroll
    for (int reg = 0; reg < 4; ++reg) {
        int id = ids4[reg];
        if (id != cur) {
            if (cur >= 0) {
                int si = cur - s_first;
                if (si < MAXSEG) {
#pragma unroll
                    for (int ot = 0; ot < 4; ++ot)
                        atomicAdd(&segacc[si * 64 + ot * 16 + n], racc[ot]);
                } else {
#pragma unroll
                    for (int ot = 0; ot < 4; ++ot)
                        atomicAdd(&out[cur * 64 + ot * 16 + n], racc[ot]);
                }
            }
            cur = id;
            racc[0] = racc[1] = racc[2] = racc[3] = 0.f;
        }
#pragma unroll
        for (int ot = 0; ot < 4; ++ot)
            racc[ot] += fmaxf(acc[ot][reg] + bv[ot], 0.f);
    }
    if (cur >= 0) {
        int si = cur - s_first;
        if (si < MAXSEG) {
#pragma unroll
            for (int ot = 0; ot < 4; ++ot)
                atomicAdd(&segacc[si * 64 + ot * 16 + n], racc[ot]);
        } else {
#pragma unroll
            for (int ot = 0; ot < 4; ++ot)
                atomicAdd(&out[cur * 64 + ot * 16 + n], racc[ot]);
        }
    }

    // ---- flush block-level segment sums (≈ span*64 global atomics) ----
    __syncthreads();
#pragma unroll
    for (int i0 = 0; i0 < (MAXSEG * 64) / 256; ++i0) {
        int i = i0 * 256 + tid;
        float v = segacc[i];
        if (v != 0.0f)
            atomicAdd(&out[(s_first + (i >> 6)) * 64 + (i & 63)], v);
    }
}

__global__ void finalize(float* __restrict__ out, int nseg) {
    int row = blockIdx.x * 4 + (threadIdx.x >> 6);
    int lane = threadIdx.x & 63;
    if (row >= nseg) return;
    float v = fmaxf(out[row * 64 + lane], 0.f);
    float m = v;
#pragma unroll
    for (int off = 32; off > 0; off >>= 1)
        m = fmaxf(m, __shfl_xor(m, off, 64));
    out[row * 64 + lane] = v / m;
}

extern "C" void kernel_launch(void* const* d_in, const int* in_sizes, int n_in,
                              void* d_out, int out_size, void* d_ws, size_t ws_size,
                              hipStream_t stream) {
    const float* x = (const float*)d_in[0];
    const float* W = (const float*)d_in[1];
    const float* b = (const float*)d_in[2];
    const int* batch = (const int*)d_in[3];
    int n_atoms = in_sizes[0] / D_IN;
    int nseg = out_size / D_OUT;
    float* out = (float*)d_out;
    ushort* Wt = (ushort*)d_ws;  // 16 KB

    hipMemsetAsync(d_out, 0, (size_t)out_size * sizeof(float), stream);
    wconv<<<dim3((D_OUT * KPAD + 255) / 256), dim3(256), 0, stream>>>(W, Wt);
    int nblocks = (n_atoms + 63) / 64;  // 64 atom rows per 256-thread block
    fused_main<<<dim3(nblocks), dim3(256), 0, stream>>>(x, Wt, b, batch, out, n_atoms);
    finalize<<<dim3((nseg + 3) / 4), dim3(256), 0, stream>>>(out, nseg);
}

// Round 4
// 656.168 us; speedup vs baseline: 1.1015x; 1.1015x over previous
//
#include <hip/hip_runtime.h>
#include <hip/hip_bf16.h>
#include <stdint.h>

#define D_IN 118
#define D_OUT 64
#define KPAD 128
#define BM 128
#define XS_STRIDE 136  // bf16 units; 68 dwords -> quad-phase LDS reads 2-way (free)
#define MAXSEG 16      // per-block LDS segment window (4 KB)

typedef __attribute__((ext_vector_type(8))) short bf16x8;
typedef __attribute__((ext_vector_type(4))) float floatx4;

// round-to-nearest-even fp32 -> bf16 (for W, cost irrelevant)
__device__ __forceinline__ uint16_t f2bf(float f) {
    uint32_t u;
    __builtin_memcpy(&u, &f, 4);
    return (uint16_t)((u + 0x7fffu + ((u >> 16) & 1u)) >> 16);
}

// cheap 2xfp32 -> packed bf16x2: +0x8000 (round-nearest ties-away) + v_perm
__device__ __forceinline__ uint32_t pack2(float a, float b) {
    uint32_t ua, ub;
    __builtin_memcpy(&ua, &a, 4);
    __builtin_memcpy(&ub, &b, 4);
    ua += 0x8000u;
    ub += 0x8000u;
    return __builtin_amdgcn_perm(ub, ua, 0x07060302);  // low=hi16(a), high=hi16(b)
}

// W -> bf16 [64 x 128] + zero the output accumulator
__global__ void wconv(const float* __restrict__ W, ushort* __restrict__ Wt,
                      float* __restrict__ out, int out_elems) {
    int idx = blockIdx.x * 256 + threadIdx.x;  // 8192 threads
    if (idx < D_OUT * KPAD) {
        int o = idx >> 7, k = idx & 127;
        float v = (k < D_IN) ? W[o * D_IN + k] : 0.f;
        Wt[idx] = f2bf(v);
    }
    for (int i = idx; i < out_elems; i += D_OUT * KPAD)
        out[i] = 0.f;
}

__global__ __launch_bounds__(256, 4) void fused_main(
    const float* __restrict__ x, const ushort* __restrict__ Wt,
    const float* __restrict__ bias, const int* __restrict__ batch,
    float* __restrict__ out, int n_atoms)
{
    __shared__ __align__(16) ushort xs[BM * XS_STRIDE];  // 34 KB
    __shared__ int ids[BM];
    __shared__ float segacc[MAXSEG * 64];                // 4 KB

    const int tid = threadIdx.x;
    const int atom0 = blockIdx.x * BM;

    if (tid < BM) {
        int a = atom0 + tid;
        ids[tid] = (a < n_atoms) ? batch[a] : -1;
    }
#pragma unroll
    for (int i = 0; i < (MAXSEG * 64) / 256; ++i)
        segacc[i * 256 + tid] = 0.0f;

    // ---- stage x -> bf16 LDS tile [128 rows x 128 K], float4 loads ----
    // task (m, c): row m, chunk c covers k = c*8 .. c*8+7
#pragma unroll
    for (int ph = 0; ph < 8; ++ph) {
        int tau = ph * 256 + tid;
        int m = tau >> 4, c = tau & 15;
        long row = atom0 + m;
        bool rok = row < n_atoms;
        const float* src = x + row * (long)D_IN + c * 8;
        float4 v0 = make_float4(0.f, 0.f, 0.f, 0.f);
        float4 v1 = make_float4(0.f, 0.f, 0.f, 0.f);
        if (rok) {
            if (c < 14) {                       // k 0..111: fully in-row
                v0 = *reinterpret_cast<const float4*>(src);
                v1 = *reinterpret_cast<const float4*>(src + 4);
            } else if (c == 14) {               // k 112..119: 118,119 are pad
                v0 = *reinterpret_cast<const float4*>(src);
                if (row + 1 < n_atoms) {        // safe to over-read into next row
                    v1 = *reinterpret_cast<const float4*>(src + 4);
                    v1.z = 0.f;
                    v1.w = 0.f;
                } else {                        // very last row: no over-read
                    float2 t = *reinterpret_cast<const float2*>(src + 4);
                    v1.x = t.x;
                    v1.y = t.y;
                }
            }                                   // c == 15: all pad (zeros)
        }
        uint4 pkd;
        pkd.x = pack2(v0.x, v0.y);
        pkd.y = pack2(v0.z, v0.w);
        pkd.z = pack2(v1.x, v1.y);
        pkd.w = pack2(v1.z, v1.w);
        *reinterpret_cast<uint4*>(&xs[m * XS_STRIDE + c * 8]) = pkd;
    }

    const int lane = tid & 63;
    const int wv = tid >> 6;
    const int n = lane & 15;   // MFMA A-row / B-col / D-col
    const int q = lane >> 4;   // quad

    __syncthreads();

    floatx4 acc[2][4];
#pragma unroll
    for (int mt = 0; mt < 2; ++mt)
#pragma unroll
        for (int ot = 0; ot < 4; ++ot)
            acc[mt][ot] = (floatx4){0.f, 0.f, 0.f, 0.f};

    // ---- MFMA: wave covers atoms [wv*32, wv*32+32) x all 64 outputs ----
    // B loaded on-demand (Wt is 16 KB, L1-hot) to keep VGPRs under 128
#pragma unroll
    for (int ks = 0; ks < 4; ++ks) {
        bf16x8 afrag[2];
#pragma unroll
        for (int mt = 0; mt < 2; ++mt) {
            int row = wv * 32 + mt * 16 + n;  // A[m=lane&15][k=q*8+j]
            afrag[mt] = *reinterpret_cast<const bf16x8*>(
                &xs[row * XS_STRIDE + ks * 32 + q * 8]);
        }
#pragma unroll
        for (int ot = 0; ot < 4; ++ot) {
            bf16x8 bfrag = *reinterpret_cast<const bf16x8*>(
                Wt + (ot * 16 + n) * KPAD + ks * 32 + q * 8);
            acc[0][ot] = __builtin_amdgcn_mfma_f32_16x16x32_bf16(
                afrag[0], bfrag, acc[0][ot], 0, 0, 0);
            acc[1][ot] = __builtin_amdgcn_mfma_f32_16x16x32_bf16(
                afrag[1], bfrag, acc[1][ot], 0, 0, 0);
        }
    }

    // ---- epilogue: bias + relu + sorted-run flush -> LDS segacc ----
    float bv[4];
#pragma unroll
    for (int ot = 0; ot < 4; ++ot) bv[ot] = bias[ot * 16 + n];

    const int s_first = ids[0];
    float racc[4] = {0.f, 0.f, 0.f, 0.f};
    int cur = ids[wv * 32 + q * 4];
#pragma unroll
    for (int mt = 0; mt < 2; ++mt) {
#pragma unroll
        for (int reg = 0; reg < 4; ++reg) {
            int r = wv * 32 + mt * 16 + q * 4 + reg;
            int id = ids[r];  // same addr across quad -> LDS broadcast
            if (id != cur) {
                if (cur >= 0) {
                    int si = cur - s_first;
                    if (si < MAXSEG) {
#pragma unroll
                        for (int ot = 0; ot < 4; ++ot)
                            atomicAdd(&segacc[si * 64 + ot * 16 + n], racc[ot]);
                    } else {
#pragma unroll
                        for (int ot = 0; ot < 4; ++ot)
                            atomicAdd(&out[cur * 64 + ot * 16 + n], racc[ot]);
                    }
                }
                cur = id;
                racc[0] = racc[1] = racc[2] = racc[3] = 0.f;
            }
#pragma unroll
            for (int ot = 0; ot < 4; ++ot)
                racc[ot] += fmaxf(acc[mt][ot][reg] + bv[ot], 0.f);
        }
    }
    if (cur >= 0) {
        int si = cur - s_first;
        if (si < MAXSEG) {
#pragma unroll
            for (int ot = 0; ot < 4; ++ot)
                atomicAdd(&segacc[si * 64 + ot * 16 + n], racc[ot]);
        } else {
#pragma unroll
            for (int ot = 0; ot < 4; ++ot)
                atomicAdd(&out[cur * 64 + ot * 16 + n], racc[ot]);
        }
    }

    // ---- flush block-level segment sums (1 atomic per nonzero seg-col) ----
    __syncthreads();
#pragma unroll
    for (int i0 = 0; i0 < (MAXSEG * 64) / 256; ++i0) {
        int i = i0 * 256 + tid;
        float v = segacc[i];
        if (v != 0.0f)
            atomicAdd(&out[(s_first + (i >> 6)) * 64 + (i & 63)], v);
    }
}

__global__ void finalize(float* __restrict__ out, int nseg) {
    int row = blockIdx.x * 4 + (threadIdx.x >> 6);
    int lane = threadIdx.x & 63;
    if (row >= nseg) return;
    float v = fmaxf(out[row * 64 + lane], 0.f);
    float m = v;
#pragma unroll
    for (int off = 32; off > 0; off >>= 1)
        m = fmaxf(m, __shfl_xor(m, off, 64));
    out[row * 64 + lane] = v / m;
}

extern "C" void kernel_launch(void* const* d_in, const int* in_sizes, int n_in,
                              void* d_out, int out_size, void* d_ws, size_t ws_size,
                              hipStream_t stream) {
    const float* x = (const float*)d_in[0];
    const float* W = (const float*)d_in[1];
    const float* b = (const float*)d_in[2];
    const int* batch = (const int*)d_in[3];
    int n_atoms = in_sizes[0] / D_IN;
    int nseg = out_size / D_OUT;
    float* out = (float*)d_out;
    ushort* Wt = (ushort*)d_ws;  // 16 KB

    wconv<<<dim3(32), dim3(256), 0, stream>>>(W, Wt, out, out_size);
    int nblocks = (n_atoms + BM - 1) / BM;
    fused_main<<<dim3(nblocks), dim3(256), 0, stream>>>(x, Wt, b, batch, out, n_atoms);
    finalize<<<dim3((nseg + 3) / 4), dim3(256), 0, stream>>>(out, nseg);
}